// Round 2
// baseline (5952.068 us; speedup 1.0000x reference)
//
#include <hip/hip_runtime.h>
#include <hip/hip_bf16.h>

// ---------------------------------------------------------------------------
// Fused attention: QKV proj (bf16 MFMA, RoPE fused in Q/K epilogue, V written
// transposed) + causal flash attention (async-staged, XOR-swizzled LDS,
// balanced grid) + output proj (fp32 out). MI355X / gfx950.
// MFMA layouts (learn_hip m89/m91/m120):
//   A-frag: A[m=lane&15][k=(lane>>4)*8+j]
//   B-frag: B[k=(lane>>4)*8+j][n=lane&15]
//   C/D   : col=lane&15, row=(lane>>4)*4+reg
// ---------------------------------------------------------------------------

typedef __bf16 bf16x8 __attribute__((ext_vector_type(8)));
typedef __bf16 bf16x4 __attribute__((ext_vector_type(4)));
typedef float  f32x4  __attribute__((ext_vector_type(4)));

#define GLD_A1(p) ((__attribute__((address_space(1))) void*)(p))
#define GLD_A3(p) ((__attribute__((address_space(3))) void*)(p))

static constexpr int   TSEQ = 2048;
static constexpr int   DM   = 4096;
static constexpr int   NH   = 32;
static constexpr int   DH   = 128;
static constexpr size_t TS  = (size_t)DM * DM;      // == B*T*DM as well
static constexpr float L2THETA = 14.287712379549449f;  // log2(20000)

// ---------------------------------------------------------------------------
// fp32 -> bf16 cast for all 5 inputs in one dispatch (all TS elems each)
// ---------------------------------------------------------------------------
__global__ __launch_bounds__(256) void cast5(const float* __restrict__ i0, const float* __restrict__ i1,
                                             const float* __restrict__ i2, const float* __restrict__ i3,
                                             const float* __restrict__ i4,
                                             __bf16* o0, __bf16* o1, __bf16* o2, __bf16* o3, __bf16* o4) {
    const float* in;
    __bf16* out;
    switch (blockIdx.y) {
        case 0:  in = i0; out = o0; break;
        case 1:  in = i1; out = o1; break;
        case 2:  in = i2; out = o2; break;
        case 3:  in = i3; out = o3; break;
        default: in = i4; out = o4; break;
    }
    size_t id = (size_t)blockIdx.x * blockDim.x + threadIdx.x;
    float4 v = ((const float4*)in)[id];
    bf16x4 o = { (__bf16)v.x, (__bf16)v.y, (__bf16)v.z, (__bf16)v.w };
    *(bf16x4*)(out + id * 4) = o;
}

// ---------------------------------------------------------------------------
// NT GEMM: C[m][n] = sum_k A[m][k] * W[n][k];  M=N=K=4096 (m97 structure).
// MODE 0 (M_ROPE): bf16 out, RoPE applied (for Q,K projections)
// MODE 1 (M_VT)  : bf16 out, transposed (B,H,Dh,T) layout (for V projection)
// MODE 2 (M_F32) : fp32 out, natural layout (final output projection)
// ---------------------------------------------------------------------------
enum { M_ROPE = 0, M_VT = 1, M_F32 = 2 };

template <int MODE>
__global__ __launch_bounds__(256) void gemm_nt(const __bf16* __restrict__ A,
                                               const __bf16* __restrict__ W,
                                               void* __restrict__ Cout) {
    constexpr int Kd = 4096, Nd = 4096;
    __shared__ alignas(16) __bf16 As[128 * 32];
    __shared__ alignas(16) __bf16 Bs[128 * 32];

    const int t = threadIdx.x, w = t >> 6, L = t & 63;
    const int lane15 = L & 15, quad = L >> 4;
    const int rowBlock = blockIdx.y * 128, colBlock = blockIdx.x * 128;
    const int wr = (w >> 1) * 64, wc = (w & 1) * 64;

    f32x4 acc[4][4] = {};

    for (int kb = 0; kb < Kd; kb += 32) {
        __syncthreads();
#pragma unroll
        for (int i = 0; i < 2; i++) {
            const int chunk = w * 128 + i * 64 + L;
            const int row = chunk >> 2, c8 = (chunk & 3) * 8;
            __builtin_amdgcn_global_load_lds(
                GLD_A1(A + (size_t)(rowBlock + row) * Kd + kb + c8),
                GLD_A3(As + (size_t)(w * 128 + i * 64) * 8), 16, 0, 0);
            __builtin_amdgcn_global_load_lds(
                GLD_A1(W + (size_t)(colBlock + row) * Kd + kb + c8),
                GLD_A3(Bs + (size_t)(w * 128 + i * 64) * 8), 16, 0, 0);
        }
        __syncthreads();

        bf16x8 a[4], b[4];
#pragma unroll
        for (int i = 0; i < 4; i++)
            a[i] = *(const bf16x8*)(As + (wr + i * 16 + lane15) * 32 + quad * 8);
#pragma unroll
        for (int j = 0; j < 4; j++)
            b[j] = *(const bf16x8*)(Bs + (wc + j * 16 + lane15) * 32 + quad * 8);
#pragma unroll
        for (int i = 0; i < 4; i++)
#pragma unroll
            for (int j = 0; j < 4; j++)
                acc[i][j] = __builtin_amdgcn_mfma_f32_16x16x32_bf16(a[i], b[j], acc[i][j], 0, 0, 0);
    }

#pragma unroll
    for (int i = 0; i < 4; i++)
#pragma unroll
        for (int j = 0; j < 4; j++)
#pragma unroll
            for (int r = 0; r < 4; r++) {
                float val = acc[i][j][r];
                const int gm = rowBlock + wr + i * 16 + quad * 4 + r;
                const int gn = colBlock + wc + j * 16 + lane15;
                if (MODE == M_ROPE) {
                    // lanes lane15 even/odd hold the RoPE pair (dims 2p, 2p+1)
                    const float partner = __shfl_xor(val, 1);
                    const int tpos = gm & (TSEQ - 1);
                    const int dim = gn & (DH - 1);
                    const float inv = exp2f(-(float)(dim & 62) * (L2THETA / 64.0f));
                    float sA, cA;
                    sincosf((float)tpos * inv, &sA, &cA);
                    val = (dim & 1) ? (val * cA + partner * sA) : (val * cA - partner * sA);
                    ((__bf16*)Cout)[(size_t)gm * Nd + gn] = (__bf16)val;
                } else if (MODE == M_VT) {
                    // V^T global layout: [(b*NH+h)*DH + d][t]
                    const int b = gm >> 11, tpos = gm & (TSEQ - 1);
                    const int h = gn >> 7, d = gn & (DH - 1);
                    ((__bf16*)Cout)[(size_t)((b * NH + h) * DH + d) * TSEQ + tpos] = (__bf16)val;
                } else {
                    ((float*)Cout)[(size_t)gm * Nd + gn] = val;
                }
            }
}

// ---------------------------------------------------------------------------
// Flash attention, causal. 512 thr (8 waves). Q tile 128 rows (16/wave),
// K tile 64 keys. K,V^T staged via global_load_lds into XOR-swizzled LDS.
// Grid (8, 64): block bx does q-tiles {bx, 15-bx} -> 34 kt-tiles every block.
// ---------------------------------------------------------------------------
__global__ __launch_bounds__(512, 4) void flash_attn(const __bf16* __restrict__ Qg,
                                                     const __bf16* __restrict__ Kg,
                                                     const __bf16* __restrict__ Vtg,
                                                     __bf16* __restrict__ Og) {
    const int bx = blockIdx.x;            // 0..7
    const int bh = blockIdx.y;            // 0..63 = b*32+h
    const size_t nbase = (size_t)(bh >> 5) * TSEQ * DM + (size_t)(bh & 31) * DH;
    const __bf16* Qp = Qg + nbase;
    const __bf16* Kp = Kg + nbase;
    const __bf16* Vtp = Vtg + (size_t)bh * DH * TSEQ;
    __bf16*       Op = Og + nbase;

    // Ks[key][dim-chunk swizzled]: elem(key, dim) at key*128 + (chunk^ (key&15))*8 + e
    // Vt[dim][key8 swizzled]     : elem(dim, key) at dim*64  + (key8 ^ (dim&7))*8 + e
    // Ps[row][key-chunk swizzled]: elem(row, key) at row*64  + (kch ^ (row&7))*8  + e
    __shared__ alignas(16) __bf16 Ks[64 * 128];
    __shared__ alignas(16) __bf16 Vt[128 * 64];
    __shared__ alignas(16) __bf16 Ps[128 * 64];

    const int t = threadIdx.x, w = t >> 6, L = t & 63;
    const int lane15 = L & 15, quad = L >> 4;
    const float scale = 0.08838834764831845f;  // 1/sqrt(128)

    for (int pass = 0; pass < 2; ++pass) {
        const int qb = pass ? (15 - bx) : bx;

        // Q A-frags in registers for the whole pass (wave owns 16 rows)
        bf16x8 aq[4];
        {
            const int qrow = qb * 128 + w * 16 + lane15;
#pragma unroll
            for (int ks = 0; ks < 4; ++ks)
                aq[ks] = *(const bf16x8*)(Qp + (size_t)qrow * DM + ks * 32 + quad * 8);
        }

        f32x4 o[8] = {};
        float m_i[4], l_i[4];
#pragma unroll
        for (int r = 0; r < 4; r++) { m_i[r] = -1e30f; l_i[r] = 0.0f; }

        const int ktmax = 2 * qb + 1;
        for (int kt = 0; kt <= ktmax; ++kt) {
            __syncthreads();  // all waves done reading Ks/Vt from previous tile

            // ---- async stage: K tile (16 KB) + V^T tile (16 KB), swizzled ----
            {
                const int i0 = w * 2;
#pragma unroll
                for (int i = 0; i < 2; ++i) {
                    const int cl = (i0 + i) * 64 + L;          // chunk-linear
                    const int keyl = cl >> 4;                  // 0..63
                    const int gch = (L & 15) ^ (keyl & 15);    // unswizzled dim chunk
                    __builtin_amdgcn_global_load_lds(
                        GLD_A1(Kp + (size_t)(kt * 64 + keyl) * DM + gch * 8),
                        GLD_A3(Ks + (i0 + i) * 512), 16, 0, 0);
                }
#pragma unroll
                for (int i = 0; i < 2; ++i) {
                    const int bl = (i0 + i) * 64 + L;          // block-linear
                    const int dim = bl >> 3;                   // 0..127
                    const int k8 = (L & 7) ^ (dim & 7);        // unswizzled key8
                    __builtin_amdgcn_global_load_lds(
                        GLD_A1(Vtp + (size_t)dim * TSEQ + kt * 64 + k8 * 8),
                        GLD_A3(Vt + (i0 + i) * 512), 16, 0, 0);
                }
            }
            __syncthreads();  // drains vmcnt -> tiles resident

            // ---- S = Q K^T (wave: 16 rows x 64 keys) ----
            f32x4 s[4] = {};
#pragma unroll
            for (int ks = 0; ks < 4; ++ks)
#pragma unroll
                for (int n = 0; n < 4; n++) {
                    const bf16x8 bk = *(const bf16x8*)(Ks + (n * 16 + lane15) * 128 +
                                                       (((ks * 4 + quad) ^ lane15) & 15) * 8);
                    s[n] = __builtin_amdgcn_mfma_f32_16x16x32_bf16(aq[ks], bk, s[n], 0, 0, 0);
                }

            // ---- scale + causal mask (only the last two kt tiles can mask) ----
            const bool diag = (kt >= 2 * qb);
#pragma unroll
            for (int n = 0; n < 4; n++) {
                const int col = kt * 64 + n * 16 + lane15;
#pragma unroll
                for (int r = 0; r < 4; r++) {
                    const int rowq = qb * 128 + w * 16 + quad * 4 + r;
                    float sv = s[n][r] * scale;
                    if (diag && col > rowq) sv = -1e30f;
                    s[n][r] = sv;
                }
            }

            // ---- online softmax ----
            float mx[4], al[4], rs[4];
#pragma unroll
            for (int r = 0; r < 4; r++)
                mx[r] = fmaxf(fmaxf(s[0][r], s[1][r]), fmaxf(s[2][r], s[3][r]));
#pragma unroll
            for (int off = 8; off >= 1; off >>= 1)
#pragma unroll
                for (int r = 0; r < 4; r++)
                    mx[r] = fmaxf(mx[r], __shfl_xor(mx[r], off));
#pragma unroll
            for (int r = 0; r < 4; r++) {
                const float mn = fmaxf(m_i[r], mx[r]);
                al[r] = __expf(m_i[r] - mn);
                m_i[r] = mn;
                rs[r] = 0.0f;
            }
            // P write: per-wave private Ps rows -> no barrier needed before PV
#pragma unroll
            for (int n = 0; n < 4; n++) {
                const int kch = n * 2 + (lane15 >> 3);   // key chunk (of 8)
#pragma unroll
                for (int r = 0; r < 4; r++) {
                    const float p = __expf(s[n][r] - m_i[r]);
                    rs[r] += p;
                    const int rl = w * 16 + quad * 4 + r;
                    Ps[rl * 64 + ((kch ^ (rl & 7)) * 8) + (lane15 & 7)] = (__bf16)p;
                }
            }
#pragma unroll
            for (int off = 8; off >= 1; off >>= 1)
#pragma unroll
                for (int r = 0; r < 4; r++)
                    rs[r] += __shfl_xor(rs[r], off);
#pragma unroll
            for (int r = 0; r < 4; r++) l_i[r] = l_i[r] * al[r] + rs[r];
#pragma unroll
            for (int d = 0; d < 8; ++d)
#pragma unroll
                for (int r = 0; r < 4; r++) o[d][r] *= al[r];

            // ---- O += P V ----
            {
                const int rl = w * 16 + lane15;
#pragma unroll
                for (int ks2 = 0; ks2 < 2; ++ks2) {
                    const bf16x8 ap = *(const bf16x8*)(Ps + rl * 64 +
                                                       (((ks2 * 4 + quad) ^ (lane15 & 7)) * 8));
#pragma unroll
                    for (int d = 0; d < 8; ++d) {
                        const bf16x8 bv = *(const bf16x8*)(Vt + (d * 16 + lane15) * 64 +
                                                           (((ks2 * 4 + quad) ^ (lane15 & 7)) * 8));
                        o[d] = __builtin_amdgcn_mfma_f32_16x16x32_bf16(ap, bv, o[d], 0, 0, 0);
                    }
                }
            }
        }

        // ---- epilogue: O / l ----
        float inv_l[4];
#pragma unroll
        for (int r = 0; r < 4; r++) inv_l[r] = 1.0f / l_i[r];
#pragma unroll
        for (int d = 0; d < 8; ++d)
#pragma unroll
            for (int r = 0; r < 4; r++) {
                const int rowq = qb * 128 + w * 16 + quad * 4 + r;
                Op[(size_t)rowq * DM + d * 16 + lane15] = (__bf16)(o[d][r] * inv_l[r]);
            }
    }
}

// ---------------------------------------------------------------------------
extern "C" void kernel_launch(void* const* d_in, const int* in_sizes, int n_in,
                              void* d_out, int out_size, void* d_ws, size_t ws_size,
                              hipStream_t stream) {
    const float* hs = (const float*)d_in[0];
    const float* Wq = (const float*)d_in[1];
    const float* Wk = (const float*)d_in[2];
    const float* Wv = (const float*)d_in[3];
    const float* Wo = (const float*)d_in[4];
    float* out = (float*)d_out;

    __bf16* hs_b = (__bf16*)d_ws;
    __bf16* wq_b = hs_b + TS;
    __bf16* wk_b = wq_b + TS;
    __bf16* wv_b = wk_b + TS;
    __bf16* wo_b = wv_b + TS;
    __bf16* Qb   = wo_b + TS;
    __bf16* Kb   = Qb + TS;
    __bf16* Vtb  = Kb + TS;   // transposed V: [(b*NH+h)*DH + d][t]
    __bf16* Ab   = Vtb + TS;
    if (ws_size < 9 * TS * sizeof(__bf16)) return;

    const dim3 blk(256);
    cast5<<<dim3((int)(TS / 4 / 256), 5), blk, 0, stream>>>(hs, Wq, Wk, Wv, Wo,
                                                            hs_b, wq_b, wk_b, wv_b, wo_b);

    const dim3 ggrid(32, 32);
    gemm_nt<M_ROPE><<<ggrid, blk, 0, stream>>>(hs_b, wq_b, (void*)Qb);
    gemm_nt<M_ROPE><<<ggrid, blk, 0, stream>>>(hs_b, wk_b, (void*)Kb);
    gemm_nt<M_VT>  <<<ggrid, blk, 0, stream>>>(hs_b, wv_b, (void*)Vtb);

    flash_attn<<<dim3(8, 64), dim3(512), 0, stream>>>(Qb, Kb, Vtb, Ab);

    gemm_nt<M_F32><<<ggrid, blk, 0, stream>>>(Ab, wo_b, (void*)out);
}